// Round 1
// baseline (336.530 us; speedup 1.0000x reference)
//
#include <hip/hip_runtime.h>

// fCGModule: Clebsch-Gordan tensor product, MAXL=5, TAUS=16, BATCH=256.
// Output = tuple out0..out5 concatenated flat; out_l shape (256, nfrag_l*256, 2l+1, 2) fp32.
// Write-bound: 239.6 MB output, ~1.25 GFLOP compute. Floor ~38us @6.3TB/s.

__device__ __constant__ double FACT[17] = {
    1.0, 1.0, 2.0, 6.0, 24.0, 120.0, 720.0, 5040.0, 40320.0, 362880.0,
    3628800.0, 39916800.0, 479001600.0, 6227020800.0, 87178291200.0,
    1307674368000.0, 20922789888000.0};

// exact Condon-Shortley CG coefficient (matches reference _cg)
__device__ double cg_coef(int l1, int l2, int l, int m1, int m2) {
    int m = m1 + m2;
    if (m > l || -m > l || l < l1 - l2 || l > l1 + l2) return 0.0;
    double pref = (double)(2 * l + 1) * FACT[l + l1 - l2] * FACT[l - l1 + l2] *
                  FACT[l1 + l2 - l] / FACT[l1 + l2 + l + 1];
    pref *= FACT[l + m] * FACT[l - m] * FACT[l1 - m1] * FACT[l1 + m1] *
            FACT[l2 - m2] * FACT[l2 + m2];
    int kmin = 0;
    if (-(l - l2 + m1) > kmin) kmin = -(l - l2 + m1);
    if (-(l - l1 - m2) > kmin) kmin = -(l - l1 - m2);
    int kmax = l1 + l2 - l;
    if (l1 - m1 < kmax) kmax = l1 - m1;
    if (l2 + m2 < kmax) kmax = l2 + m2;
    double s = 0.0;
    for (int k = kmin; k <= kmax; ++k) {
        double d = FACT[k] * FACT[l1 + l2 - l - k] * FACT[l1 - m1 - k] *
                   FACT[l2 + m2 - k] * FACT[l - l2 + m1 + k] * FACT[l - l1 - m2 + k];
        s += ((k & 1) ? -1.0 : 1.0) / d;
    }
    return sqrt(pref) * s;
}

// ---- compile-time layout tables (derived from _TRIPLES ordering) ----
// out_l flat base offsets (floats) and per-batch strides (floats)
constexpr int OUT_BASE[6]  = {0, 786432, 4718592, 13238272, 26083328, 42598400};
constexpr int STRIDE_B[6]  = {3072, 15360, 33280, 50176, 64512, 67584}; // NCH_l*(2l+1)*2

// 21 (l1,l2) pairs ordered by descending work (heavy blocks dispatch first)
constexpr int PL1[21] = {5,5,4,4,5,3,4,3,5,2,4,5,3,2,1,5,4,3,2,1,0};
constexpr int PL2[21] = {5,4,4,3,3,3,2,2,2,2,1,1,1,1,1,0,0,0,0,0,0};
// fragment index of triple (l1,l2,l) within output l's channel concat (-1 = l not produced)
constexpr int PFRAG[21][6] = {
    { 5,  9, 12, 13, 13, 11},  // (5,5)
    {-1,  8, 11, 12, 12, 10},  // (5,4)
    { 4,  7,  9,  9,  8,  5},  // (4,4)
    {-1,  6,  8,  8,  7,  4},  // (4,3)
    {-1, -1, 10, 11, 11,  9},  // (5,3)
    { 3,  5,  6,  5,  3,  1},  // (3,3)
    {-1, -1,  7,  7,  6,  3},  // (4,2)
    {-1,  4,  5,  4,  2,  0},  // (3,2)
    {-1, -1, -1, 10, 10,  8},  // (5,2)
    { 2,  3,  3,  1,  0, -1},  // (2,2)
    {-1, -1, -1,  6,  5,  2},  // (4,1)
    {-1, -1, -1, -1,  9,  7},  // (5,1)
    {-1, -1,  4,  3,  1, -1},  // (3,1)
    {-1,  2,  2,  0, -1, -1},  // (2,1)
    { 1,  1,  0, -1, -1, -1},  // (1,1)
    {-1, -1, -1, -1, -1,  6},  // (5,0)
    {-1, -1, -1, -1,  4, -1},  // (4,0)
    {-1, -1, -1,  2, -1, -1},  // (3,0)
    {-1, -1,  1, -1, -1, -1},  // (2,0)
    {-1,  0, -1, -1, -1, -1},  // (1,0)
    { 0, -1, -1, -1, -1, -1},  // (0,0)
};

template <int PAIR>
__device__ __forceinline__ void pair_body(const float* const acts[6],
                                          float* __restrict__ out,
                                          int blk, int tid, float* cg) {
    constexpr int L1   = PL1[PAIR];
    constexpr int L2   = PL2[PAIR];
    constexpr int LMIN = L1 - L2;
    constexpr int LMAX = (L1 + L2 < 5) ? (L1 + L2) : 5;
    constexpr int N1   = 2 * L1 + 1;
    constexpr int N2   = 2 * L2 + 1;
    constexpr int NL   = LMAX - LMIN + 1;
    constexpr int NENT = NL * N1 * N2;
    constexpr int ACCN = (LMAX + 1) * (LMAX + 1) - LMIN * LMIN; // (l,m) slots

    // block prologue: fill this pair's CG table in LDS (<=3 evals/thread)
    for (int e = tid; e < NENT; e += 256) {
        int li = e / (N1 * N2);
        int r  = e - li * (N1 * N2);
        int p  = r / N2;
        int q  = r - p * N2;
        cg[e] = (float)cg_coef(L1, L2, LMIN + li, p - L1, q - L2);
    }
    __syncthreads();

    int t  = blk * 256 + tid;      // 0..65535
    int b  = t >> 8;               // batch
    int ii = t & 255;              // i*16+j
    int i  = ii >> 4;
    int j  = ii & 15;

    const float2* __restrict__ z1p =
        (const float2*)(acts[L1] + (size_t)(b * 16 + i) * N1 * 2);
    const float2* __restrict__ z2p =
        (const float2*)(acts[L2] + (size_t)(b * 16 + j) * N2 * 2);
    float2 z1[N1], z2[N2];
#pragma unroll
    for (int p = 0; p < N1; ++p) z1[p] = z1p[p];
#pragma unroll
    for (int q = 0; q < N2; ++q) z2[q] = z2p[q];

    float accr[ACCN], acci[ACCN];
#pragma unroll
    for (int k = 0; k < ACCN; ++k) { accr[k] = 0.f; acci[k] = 0.f; }

#pragma unroll
    for (int p = 0; p < N1; ++p) {
#pragma unroll
        for (int q = 0; q < N2; ++q) {
            float wr = z1[p].x * z2[q].x - z1[p].y * z2[q].y;
            float wi = z1[p].x * z2[q].y + z1[p].y * z2[q].x;
            int m  = (p - L1) + (q - L2);   // folds per unrolled iter
            int am = m < 0 ? -m : m;
#pragma unroll
            for (int l = LMIN; l <= LMAX; ++l) {
                if (l >= am) {
                    float c = cg[(l - LMIN) * N1 * N2 + p * N2 + q]; // LDS broadcast
                    int slot = (l * l - LMIN * LMIN) + (m + l);      // folds
                    accr[slot] += c * wr;
                    acci[slot] += c * wi;
                }
            }
        }
    }

    // epilogue: one contiguous (2l+1) float2 run per output l
#pragma unroll
    for (int l = LMIN; l <= LMAX; ++l) {
        float2* __restrict__ o = (float2*)(out + OUT_BASE[l]) +
            ((size_t)b * (STRIDE_B[l] / 2) +
             (size_t)(PFRAG[PAIR][l] * 256 + ii) * (2 * l + 1));
#pragma unroll
        for (int mm = 0; mm <= 2 * l; ++mm) {
            int slot = (l * l - LMIN * LMIN) + mm;
            o[mm] = make_float2(accr[slot], acci[slot]);
        }
    }
}

__global__ __launch_bounds__(256) void fCG_kernel(
    const float* __restrict__ a0, const float* __restrict__ a1,
    const float* __restrict__ a2, const float* __restrict__ a3,
    const float* __restrict__ a4, const float* __restrict__ a5,
    float* __restrict__ out) {
    __shared__ float cg[726]; // max pair (5,5): 6*11*11
    const float* acts[6] = {a0, a1, a2, a3, a4, a5};
    int pair = blockIdx.x >> 8;   // 256 blocks per pair, 65536 threads = B*16*16
    int blk  = blockIdx.x & 255;
    int tid  = threadIdx.x;
    switch (pair) {
        case 0:  pair_body<0>(acts, out, blk, tid, cg); break;
        case 1:  pair_body<1>(acts, out, blk, tid, cg); break;
        case 2:  pair_body<2>(acts, out, blk, tid, cg); break;
        case 3:  pair_body<3>(acts, out, blk, tid, cg); break;
        case 4:  pair_body<4>(acts, out, blk, tid, cg); break;
        case 5:  pair_body<5>(acts, out, blk, tid, cg); break;
        case 6:  pair_body<6>(acts, out, blk, tid, cg); break;
        case 7:  pair_body<7>(acts, out, blk, tid, cg); break;
        case 8:  pair_body<8>(acts, out, blk, tid, cg); break;
        case 9:  pair_body<9>(acts, out, blk, tid, cg); break;
        case 10: pair_body<10>(acts, out, blk, tid, cg); break;
        case 11: pair_body<11>(acts, out, blk, tid, cg); break;
        case 12: pair_body<12>(acts, out, blk, tid, cg); break;
        case 13: pair_body<13>(acts, out, blk, tid, cg); break;
        case 14: pair_body<14>(acts, out, blk, tid, cg); break;
        case 15: pair_body<15>(acts, out, blk, tid, cg); break;
        case 16: pair_body<16>(acts, out, blk, tid, cg); break;
        case 17: pair_body<17>(acts, out, blk, tid, cg); break;
        case 18: pair_body<18>(acts, out, blk, tid, cg); break;
        case 19: pair_body<19>(acts, out, blk, tid, cg); break;
        case 20: pair_body<20>(acts, out, blk, tid, cg); break;
        default: break;
    }
}

extern "C" void kernel_launch(void* const* d_in, const int* in_sizes, int n_in,
                              void* d_out, int out_size, void* d_ws, size_t ws_size,
                              hipStream_t stream) {
    const float* a0 = (const float*)d_in[0];
    const float* a1 = (const float*)d_in[1];
    const float* a2 = (const float*)d_in[2];
    const float* a3 = (const float*)d_in[3];
    const float* a4 = (const float*)d_in[4];
    const float* a5 = (const float*)d_in[5];
    float* out = (float*)d_out;
    // 21 pairs x 256 blocks x 256 threads; every output element written exactly once
    fCG_kernel<<<dim3(21 * 256), dim3(256), 0, stream>>>(a0, a1, a2, a3, a4, a5, out);
}

// Round 2
// 324.325 us; speedup vs baseline: 1.0376x; 1.0376x over previous
//
#include <hip/hip_runtime.h>

// fCGModule: Clebsch-Gordan tensor product, MAXL=5, TAUS=16, BATCH=256.
// Output = tuple out0..out5 concatenated flat; out_l shape (256, nfrag_l*256, 2l+1, 2) fp32.
// Write-bound: 239.6 MB output. Floor ~38us @6.3TB/s.
// R2: per-l accumulation + LDS-staged float4-coalesced epilogue (R1 scattered
// float2 stores caused 1.46x write amplification + store-queue stalls).

__device__ __constant__ double FACT[17] = {
    1.0, 1.0, 2.0, 6.0, 24.0, 120.0, 720.0, 5040.0, 40320.0, 362880.0,
    3628800.0, 39916800.0, 479001600.0, 6227020800.0, 87178291200.0,
    1307674368000.0, 20922789888000.0};

// exact Condon-Shortley CG coefficient (matches reference _cg)
__device__ double cg_coef(int l1, int l2, int l, int m1, int m2) {
    int m = m1 + m2;
    if (m > l || -m > l || l < l1 - l2 || l > l1 + l2) return 0.0;
    double pref = (double)(2 * l + 1) * FACT[l + l1 - l2] * FACT[l - l1 + l2] *
                  FACT[l1 + l2 - l] / FACT[l1 + l2 + l + 1];
    pref *= FACT[l + m] * FACT[l - m] * FACT[l1 - m1] * FACT[l1 + m1] *
            FACT[l2 - m2] * FACT[l2 + m2];
    int kmin = 0;
    if (-(l - l2 + m1) > kmin) kmin = -(l - l2 + m1);
    if (-(l - l1 - m2) > kmin) kmin = -(l - l1 - m2);
    int kmax = l1 + l2 - l;
    if (l1 - m1 < kmax) kmax = l1 - m1;
    if (l2 + m2 < kmax) kmax = l2 + m2;
    double s = 0.0;
    for (int k = kmin; k <= kmax; ++k) {
        double d = FACT[k] * FACT[l1 + l2 - l - k] * FACT[l1 - m1 - k] *
                   FACT[l2 + m2 - k] * FACT[l - l2 + m1 + k] * FACT[l - l1 - m2 + k];
        s += ((k & 1) ? -1.0 : 1.0) / d;
    }
    return sqrt(pref) * s;
}

// ---- compile-time layout tables (derived from _TRIPLES ordering; validated R1) ----
constexpr int OUT_BASE[6]  = {0, 786432, 4718592, 13238272, 26083328, 42598400};
constexpr int STRIDE_B[6]  = {3072, 15360, 33280, 50176, 64512, 67584}; // NCH_l*(2l+1)*2

// 21 (l1,l2) pairs ordered by descending work (heavy blocks dispatch first)
constexpr int PL1[21] = {5,5,4,4,5,3,4,3,5,2,4,5,3,2,1,5,4,3,2,1,0};
constexpr int PL2[21] = {5,4,4,3,3,3,2,2,2,2,1,1,1,1,1,0,0,0,0,0,0};
constexpr int PFRAG[21][6] = {
    { 5,  9, 12, 13, 13, 11},  // (5,5)
    {-1,  8, 11, 12, 12, 10},  // (5,4)
    { 4,  7,  9,  9,  8,  5},  // (4,4)
    {-1,  6,  8,  8,  7,  4},  // (4,3)
    {-1, -1, 10, 11, 11,  9},  // (5,3)
    { 3,  5,  6,  5,  3,  1},  // (3,3)
    {-1, -1,  7,  7,  6,  3},  // (4,2)
    {-1,  4,  5,  4,  2,  0},  // (3,2)
    {-1, -1, -1, 10, 10,  8},  // (5,2)
    { 2,  3,  3,  1,  0, -1},  // (2,2)
    {-1, -1, -1,  6,  5,  2},  // (4,1)
    {-1, -1, -1, -1,  9,  7},  // (5,1)
    {-1, -1,  4,  3,  1, -1},  // (3,1)
    {-1,  2,  2,  0, -1, -1},  // (2,1)
    { 1,  1,  0, -1, -1, -1},  // (1,1)
    {-1, -1, -1, -1, -1,  6},  // (5,0)
    {-1, -1, -1, -1,  4, -1},  // (4,0)
    {-1, -1, -1,  2, -1, -1},  // (3,0)
    {-1, -1,  1, -1, -1, -1},  // (2,0)
    {-1,  0, -1, -1, -1, -1},  // (1,0)
    { 0, -1, -1, -1, -1, -1},  // (0,0)
};

template <int PAIR>
__device__ __forceinline__ void pair_body(const float* const acts[6],
                                          float* __restrict__ out,
                                          int b, int tid, float* cg, float* stage) {
    constexpr int L1   = PL1[PAIR];
    constexpr int L2   = PL2[PAIR];
    constexpr int LMIN = L1 - L2;
    constexpr int LMAX = (L1 + L2 < 5) ? (L1 + L2) : 5;
    constexpr int N1   = 2 * L1 + 1;
    constexpr int N2   = 2 * L2 + 1;
    constexpr int NENT = (LMAX - LMIN + 1) * N1 * N2;

    // block prologue: fill this pair's CG table [l][p][q] in LDS
    for (int e = tid; e < NENT; e += 256) {
        int li = e / (N1 * N2);
        int r  = e - li * (N1 * N2);
        int p  = r / N2;
        int q  = r - p * N2;
        cg[e] = (float)cg_coef(L1, L2, LMIN + li, p - L1, q - L2);
    }
    __syncthreads();

    int i = tid >> 4;   // channel of act[L1]
    int j = tid & 15;   // channel of act[L2]

    const float2* __restrict__ z1p =
        (const float2*)(acts[L1] + (size_t)(b * 16 + i) * N1 * 2);
    const float2* __restrict__ z2p =
        (const float2*)(acts[L2] + (size_t)(b * 16 + j) * N2 * 2);
    float2 z1[N1], z2[N2];
#pragma unroll
    for (int p = 0; p < N1; ++p) z1[p] = z1p[p];
#pragma unroll
    for (int q = 0; q < N2; ++q) z2[q] = z2p[q];

    // one pass per output l: accumulate (2l+1) complex values in regs,
    // stage block-contiguous region in LDS, copy out float4-coalesced.
#pragma unroll
    for (int l = LMIN; l <= LMAX; ++l) {
        const int NM = 2 * l + 1;
        float ar[11], ai[11];
#pragma unroll
        for (int k = 0; k < NM; ++k) { ar[k] = 0.f; ai[k] = 0.f; }

#pragma unroll
        for (int p = 0; p < N1; ++p) {
#pragma unroll
            for (int q = 0; q < N2; ++q) {
                int m  = (p - L1) + (q - L2);   // folds per unrolled iter
                int am = m < 0 ? -m : m;
                if (am <= l) {
                    float c  = cg[(l - LMIN) * N1 * N2 + p * N2 + q]; // LDS broadcast
                    float wr = z1[p].x * z2[q].x - z1[p].y * z2[q].y;
                    float wi = z1[p].x * z2[q].y + z1[p].y * z2[q].x;
                    ar[m + l] += c * wr;
                    ai[m + l] += c * wi;
                }
            }
        }

        // stage: thread tid owns (2l+1) consecutive float2 (2-way bank alias max = free)
        float2* st = (float2*)stage + tid * NM;
#pragma unroll
        for (int k = 0; k < NM; ++k) st[k] = make_float2(ar[k], ai[k]);
        __syncthreads();

        // coalesced copy: 256*(2l+1) float2 = 128*(2l+1) float4, lane-contiguous
        const float4* __restrict__ s4 = (const float4*)stage;
        float4* __restrict__ d4 = (float4*)(out + OUT_BASE[l] +
            (size_t)b * STRIDE_B[l] + (size_t)PFRAG[PAIR][l] * 512 * NM);
        const int cnt = 128 * NM;
        for (int k = tid; k < cnt; k += 256) d4[k] = s4[k];
        __syncthreads();   // staging buffer reused next l
    }
}

__global__ __launch_bounds__(256, 4) void fCG_kernel(
    const float* __restrict__ a0, const float* __restrict__ a1,
    const float* __restrict__ a2, const float* __restrict__ a3,
    const float* __restrict__ a4, const float* __restrict__ a5,
    float* __restrict__ out) {
    __shared__ float cg[726];                      // max pair (5,5): 6*11*11
    __shared__ __align__(16) float stage[5632];    // max: 256*(2*5+1)*2 floats
    const float* acts[6] = {a0, a1, a2, a3, a4, a5};
    int pair = blockIdx.x >> 8;   // 256 blocks per pair (one per batch element)
    int b    = blockIdx.x & 255;
    int tid  = threadIdx.x;
    switch (pair) {
        case 0:  pair_body<0>(acts, out, b, tid, cg, stage); break;
        case 1:  pair_body<1>(acts, out, b, tid, cg, stage); break;
        case 2:  pair_body<2>(acts, out, b, tid, cg, stage); break;
        case 3:  pair_body<3>(acts, out, b, tid, cg, stage); break;
        case 4:  pair_body<4>(acts, out, b, tid, cg, stage); break;
        case 5:  pair_body<5>(acts, out, b, tid, cg, stage); break;
        case 6:  pair_body<6>(acts, out, b, tid, cg, stage); break;
        case 7:  pair_body<7>(acts, out, b, tid, cg, stage); break;
        case 8:  pair_body<8>(acts, out, b, tid, cg, stage); break;
        case 9:  pair_body<9>(acts, out, b, tid, cg, stage); break;
        case 10: pair_body<10>(acts, out, b, tid, cg, stage); break;
        case 11: pair_body<11>(acts, out, b, tid, cg, stage); break;
        case 12: pair_body<12>(acts, out, b, tid, cg, stage); break;
        case 13: pair_body<13>(acts, out, b, tid, cg, stage); break;
        case 14: pair_body<14>(acts, out, b, tid, cg, stage); break;
        case 15: pair_body<15>(acts, out, b, tid, cg, stage); break;
        case 16: pair_body<16>(acts, out, b, tid, cg, stage); break;
        case 17: pair_body<17>(acts, out, b, tid, cg, stage); break;
        case 18: pair_body<18>(acts, out, b, tid, cg, stage); break;
        case 19: pair_body<19>(acts, out, b, tid, cg, stage); break;
        case 20: pair_body<20>(acts, out, b, tid, cg, stage); break;
        default: break;
    }
}

extern "C" void kernel_launch(void* const* d_in, const int* in_sizes, int n_in,
                              void* d_out, int out_size, void* d_ws, size_t ws_size,
                              hipStream_t stream) {
    const float* a0 = (const float*)d_in[0];
    const float* a1 = (const float*)d_in[1];
    const float* a2 = (const float*)d_in[2];
    const float* a3 = (const float*)d_in[3];
    const float* a4 = (const float*)d_in[4];
    const float* a5 = (const float*)d_in[5];
    float* out = (float*)d_out;
    // 21 pairs x 256 blocks (one per batch) x 256 threads (i*16+j)
    fCG_kernel<<<dim3(21 * 256), dim3(256), 0, stream>>>(a0, a1, a2, a3, a4, a5, out);
}